// Round 7
// baseline (500.244 us; speedup 1.0000x reference)
//
#include <hip/hip_runtime.h>
#include <hip/hip_fp16.h>
#include <cmath>

// B=2, H=8, S=4096, d=64; fp32 in/out.
// e = (Q@K)/sqrt(512); a = softmax over HEADS; o = a@V.
//
// R14: two-pass barrier-free decomposition. Lesson from R7-R13: every fused
// variant is barrier-lockstep bound (~280us floor, all pipes <45% busy). The
// only cross-head quantity is Z[b,s,t] = sum_h exp(e_h). So:
//   z_pass : one wave computes e for ALL 8 heads at a (32s x 32t) tile via
//            swapped QK^T + kperm (R12/R13-verified); Z sum is LANE-LOCAL.
//            Stores w = rcp(Z) as packed-bf16 uint4 in the exact lane layout
//            pv_pass consumes. No LDS, no barriers.
//   pv_pass: wave = (head, 32 s-rows), loops all t: recompute QK^T (bit-
//            identical), exp2, multiply by streamed w, PV, write O directly.
//            No LDS, no barriers, no partials, no reduce kernel.
// MFMA work doubles (QK^T twice) -- it was only 10% utilized; barriers were
// the disease. Workspace = Kt/Vt 16MB + Wq 67MB = 83,886,080 B (= R7's
// proven-available size exactly).
#define S_LEN 4096
#define NHEAD 8
#define HEADD 64
#define KPRE 0.0637588696f           // (1/sqrt(512)) * log2(e)

#define KT_BYTES (2ull * NHEAD * S_LEN * HEADD * 2)   // 8,388,608 bf16 K^T [t][k]
#define VT_OFF   KT_BYTES
#define WQ_OFF   (2 * KT_BYTES)                        // 16,777,216
#define WQ_BYTES (2ull * S_LEN * S_LEN * 2)            // 67,108,864 (bf16 w)
#define WS_FULL  (WQ_OFF + WQ_BYTES)                   // 83,886,080

typedef __attribute__((ext_vector_type(8))) short        short8;
typedef __attribute__((ext_vector_type(4))) float        float4v;
typedef __attribute__((ext_vector_type(4))) unsigned int uint4v;

__device__ __forceinline__ unsigned short f2bf(float f) {  // fp32 -> bf16 RNE
  unsigned int u = __float_as_uint(f);
  u += 0x7FFFu + ((u >> 16) & 1u);
  return (unsigned short)(u >> 16);
}

__device__ __forceinline__ unsigned int pkbf(float lo, float hi) {  // 2xfp32 -> packed bf16
  return __builtin_amdgcn_perm(__float_as_uint(hi) + 0x8000u,
                               __float_as_uint(lo) + 0x8000u, 0x07060302u);
}

// ---------------- pre-pass: LDS-free, float4 reads, in-register 8x4 transpose,
// b128 global writes. 1024 blocks x 256 thr (512 K-blocks, 512 V-blocks).
// K [bh,64,4096] f32 -> Kt [bh,4096,64] bf16*KPRE ; V [bh,4096,64] f32 -> Vt [bh,64,4096] bf16
__global__ __launch_bounds__(256)
void prepass_cvt(const float* __restrict__ K, const float* __restrict__ V,
                 unsigned short* __restrict__ Kt, unsigned short* __restrict__ Vt) {
  const int tid  = threadIdx.x;
  const int wave = tid >> 6, lane = tid & 63;
  const int isV  = blockIdx.x >> 9;
  const int idx  = blockIdx.x & 511;
  const int bh   = idx >> 5;                       // 16 bh
  const int t0   = (idx & 31) * 128 + wave * 32;   // block covers 128 t; wave covers 32 t
  if (!isV) {
    const float* in = K + (size_t)bh * HEADD * S_LEN;       // [k][t]
    unsigned short* out = Kt + (size_t)bh * S_LEN * HEADD;  // [t][k]
    const int koct = lane >> 3;          // k = koct*8 + j
    const int kt4  = (lane & 7) * 4;     // 4 t per lane
    float buf[8][4];
#pragma unroll
    for (int j = 0; j < 8; ++j) {
      float4v v = *(const float4v*)(in + (size_t)(koct * 8 + j) * S_LEN + t0 + kt4);
      buf[j][0] = v[0]; buf[j][1] = v[1]; buf[j][2] = v[2]; buf[j][3] = v[3];
    }
#pragma unroll
    for (int c = 0; c < 4; ++c) {
      short8 f;
#pragma unroll
      for (int j = 0; j < 8; ++j) f[j] = (short)f2bf(buf[j][c] * KPRE);
      *(short8*)(out + (size_t)(t0 + kt4 + c) * HEADD + koct * 8) = f;
    }
  } else {
    const float* in = V + (size_t)bh * S_LEN * HEADD;       // [t][d]
    unsigned short* out = Vt + (size_t)bh * HEADD * S_LEN;  // [d][t]
    const int vdq = lane & 15;           // d = vdq*4 + c
    const int vtg = lane >> 4;           // t = t0 + vtg*8 + j
    float buf[8][4];
#pragma unroll
    for (int j = 0; j < 8; ++j) {
      float4v v = *(const float4v*)(in + (size_t)(t0 + vtg * 8 + j) * HEADD + vdq * 4);
      buf[j][0] = v[0]; buf[j][1] = v[1]; buf[j][2] = v[2]; buf[j][3] = v[3];
    }
#pragma unroll
    for (int c = 0; c < 4; ++c) {
      short8 f;
#pragma unroll
      for (int j = 0; j < 8; ++j) f[j] = (short)f2bf(buf[j][c]);
      *(short8*)(out + (size_t)(vdq * 4 + c) * S_LEN + t0 + vtg * 8) = f;
    }
  }
}

// ---------------- z_pass: 2048 blocks x 256 thr (4 waves). Wave covers
// (b, 32 s-rows, 4 t-tiles of 32) x ALL 8 heads. Lane-local Z sum; stores
// w = rcp(Z) packed bf16, lane-linear. blockIdx = thi<<10 | s32<<3 | combo,
// combo = b*4 + (toct&3) -> XCD-pinned K slice (1MB, L2-resident).
__global__ __launch_bounds__(256)
void z_pass(const float* __restrict__ Q, const unsigned short* __restrict__ Kt,
            unsigned int* __restrict__ Wq) {
  const int tid  = threadIdx.x;
  const int w    = tid >> 6;
  const int lane = tid & 63;
  const int quad = lane >> 4;
  const int l15  = lane & 15;
  const int combo = blockIdx.x & 7;
  const int b    = combo >> 2;
  const int toct = (combo & 3) | (((blockIdx.x >> 10) & 1) << 2);
  const int s32  = (blockIdx.x >> 3) & 127;
  const int s0   = s32 * 32;
  const int tt0  = toct * 16 + w * 4;
  // A-frag row perm (R12/R13-verified): slot (quad, r of e0/e1) <-> t = 8q + r (+4)
  const int kperm = ((l15 >> 2) << 3) + (l15 & 3);

  float zacc[4][2][8];
#pragma unroll
  for (int i = 0; i < 4; ++i)
#pragma unroll
    for (int ss = 0; ss < 2; ++ss)
#pragma unroll
      for (int j = 0; j < 8; ++j) zacc[i][ss][j] = 0.f;

  for (int h = 0; h < NHEAD; ++h) {
    // Q B-frags for this head (n=l15 s-row, k = kk*32+quad*8+j)
    short8 qf[2][2];
#pragma unroll
    for (int ss = 0; ss < 2; ++ss)
#pragma unroll
      for (int kk = 0; kk < 2; ++kk) {
        const float* p = Q + ((size_t)(b * NHEAD + h) * S_LEN + s0 + ss * 16 + l15) * HEADD
                           + kk * 32 + quad * 8;
        float4v a0 = *(const float4v*)p;
        float4v a1 = *(const float4v*)(p + 4);
        short8 f;
        f[0] = (short)f2bf(a0[0]); f[1] = (short)f2bf(a0[1]);
        f[2] = (short)f2bf(a0[2]); f[3] = (short)f2bf(a0[3]);
        f[4] = (short)f2bf(a1[0]); f[5] = (short)f2bf(a1[1]);
        f[6] = (short)f2bf(a1[2]); f[7] = (short)f2bf(a1[3]);
        qf[ss][kk] = f;
      }
    const unsigned short* Kth = Kt + (size_t)(b * NHEAD + h) * S_LEN * HEADD;
#pragma unroll
    for (int i = 0; i < 4; ++i) {
      const unsigned short* Kp = Kth + (size_t)((tt0 + i) * 32 + kperm) * HEADD + quad * 8;
      short8 k00 = *(const short8*)(Kp);
      short8 k01 = *(const short8*)(Kp + 32);
      short8 k10 = *(const short8*)(Kp + 4 * HEADD);
      short8 k11 = *(const short8*)(Kp + 4 * HEADD + 32);
#pragma unroll
      for (int ss = 0; ss < 2; ++ss) {
        float4v e0 = (float4v){0.f, 0.f, 0.f, 0.f};
        float4v e1 = (float4v){0.f, 0.f, 0.f, 0.f};
        e0 = __builtin_amdgcn_mfma_f32_16x16x32_bf16(k00, qf[ss][0], e0, 0, 0, 0);
        e0 = __builtin_amdgcn_mfma_f32_16x16x32_bf16(k01, qf[ss][1], e0, 0, 0, 0);
        e1 = __builtin_amdgcn_mfma_f32_16x16x32_bf16(k10, qf[ss][0], e1, 0, 0, 0);
        e1 = __builtin_amdgcn_mfma_f32_16x16x32_bf16(k11, qf[ss][1], e1, 0, 0, 0);
#pragma unroll
        for (int r = 0; r < 4; ++r) {
          zacc[i][ss][r]     += exp2f(e0[r]);   // t = 8q + r
          zacc[i][ss][4 + r] += exp2f(e1[r]);   // t = 8q + 4 + r
        }
      }
    }
  }

  // store w = rcp(Z), packed bf16 pairs, lane-linear uint4 per (s16,tt)
#pragma unroll
  for (int i = 0; i < 4; ++i)
#pragma unroll
    for (int ss = 0; ss < 2; ++ss) {
      float w0 = __builtin_amdgcn_rcpf(zacc[i][ss][0]);
      float w1 = __builtin_amdgcn_rcpf(zacc[i][ss][1]);
      float w2 = __builtin_amdgcn_rcpf(zacc[i][ss][2]);
      float w3 = __builtin_amdgcn_rcpf(zacc[i][ss][3]);
      float w4 = __builtin_amdgcn_rcpf(zacc[i][ss][4]);
      float w5 = __builtin_amdgcn_rcpf(zacc[i][ss][5]);
      float w6 = __builtin_amdgcn_rcpf(zacc[i][ss][6]);
      float w7 = __builtin_amdgcn_rcpf(zacc[i][ss][7]);
      uint4v pk = (uint4v){pkbf(w0, w1), pkbf(w2, w3), pkbf(w4, w5), pkbf(w6, w7)};
      unsigned int* p = Wq + ((((size_t)b * 256 + (s32 * 2 + ss)) * 128 + (tt0 + i)) * 64
                              + lane) * 4;
      *(uint4v*)p = pk;
    }
}

// ---------------- pv_pass: 256 blocks x 512 thr (8 waves = 8 heads).
// Wave = (b, head, 32 s-rows), loops all 128 t-tiles. Recomputes QK^T
// (bit-identical to z_pass), exp2, multiplies by streamed w, PV, writes O
// directly ([B,H,S,d] raw contiguous). No LDS, no barriers, no partials.
__global__ __launch_bounds__(512)
void pv_pass(const float* __restrict__ Q, const unsigned short* __restrict__ Kt,
             const unsigned short* __restrict__ Vt, const unsigned int* __restrict__ Wq,
             float* __restrict__ O) {
  const int tid  = threadIdx.x;
  const int h    = tid >> 6;
  const int lane = tid & 63;
  const int quad = lane >> 4;
  const int l15  = lane & 15;
  const int b    = blockIdx.x & 1;
  const int s32  = blockIdx.x >> 1;
  const int s0   = s32 * 32;
  const int kperm = ((l15 >> 2) << 3) + (l15 & 3);

  const float* Qg = Q + (size_t)(b * NHEAD + h) * S_LEN * HEADD;
  const unsigned short* Kth = Kt + (size_t)(b * NHEAD + h) * S_LEN * HEADD;  // [t][k]
  const unsigned short* Vth = Vt + (size_t)(b * NHEAD + h) * HEADD * S_LEN;  // [d][t]

  short8 qf[2][2];
#pragma unroll
  for (int ss = 0; ss < 2; ++ss)
#pragma unroll
    for (int kk = 0; kk < 2; ++kk) {
      const float* p = Qg + (size_t)(s0 + ss * 16 + l15) * HEADD + kk * 32 + quad * 8;
      float4v a0 = *(const float4v*)p;
      float4v a1 = *(const float4v*)(p + 4);
      short8 f;
      f[0] = (short)f2bf(a0[0]); f[1] = (short)f2bf(a0[1]);
      f[2] = (short)f2bf(a0[2]); f[3] = (short)f2bf(a0[3]);
      f[4] = (short)f2bf(a1[0]); f[5] = (short)f2bf(a1[1]);
      f[6] = (short)f2bf(a1[2]); f[7] = (short)f2bf(a1[3]);
      qf[ss][kk] = f;
    }

  // acc[ss][df] = o[s = s0+ss*16+quad*4+r][d = df*16+l15]
  float4v acc[2][4];
#pragma unroll
  for (int ss = 0; ss < 2; ++ss)
#pragma unroll
    for (int df = 0; df < 4; ++df)
      acc[ss][df] = (float4v){0.f, 0.f, 0.f, 0.f};

  const unsigned int* w0base = Wq + (((size_t)b * 256 + (s32 * 2 + 0)) * 128) * 256 + lane * 4;
  const unsigned int* w1base = Wq + (((size_t)b * 256 + (s32 * 2 + 1)) * 128) * 256 + lane * 4;

  for (int tt = 0; tt < S_LEN / 32; ++tt) {
    const unsigned short* Kp = Kth + (size_t)(tt * 32 + kperm) * HEADD + quad * 8;
    short8 k00 = *(const short8*)(Kp);
    short8 k01 = *(const short8*)(Kp + 32);
    short8 k10 = *(const short8*)(Kp + 4 * HEADD);
    short8 k11 = *(const short8*)(Kp + 4 * HEADD + 32);
    uint4v wq[2];
    wq[0] = *(const uint4v*)(w0base + tt * 256);
    wq[1] = *(const uint4v*)(w1base + tt * 256);
    short8 vf[4];
#pragma unroll
    for (int df = 0; df < 4; ++df)
      vf[df] = *(const short8*)(Vth + (size_t)(df * 16 + l15) * S_LEN + tt * 32 + quad * 8);

    short8 pf[2];
#pragma unroll
    for (int ss = 0; ss < 2; ++ss) {
      float4v e0 = (float4v){0.f, 0.f, 0.f, 0.f};
      float4v e1 = (float4v){0.f, 0.f, 0.f, 0.f};
      e0 = __builtin_amdgcn_mfma_f32_16x16x32_bf16(k00, qf[ss][0], e0, 0, 0, 0);
      e0 = __builtin_amdgcn_mfma_f32_16x16x32_bf16(k01, qf[ss][1], e0, 0, 0, 0);
      e1 = __builtin_amdgcn_mfma_f32_16x16x32_bf16(k10, qf[ss][0], e1, 0, 0, 0);
      e1 = __builtin_amdgcn_mfma_f32_16x16x32_bf16(k11, qf[ss][1], e1, 0, 0, 0);
      float p0 = exp2f(e0[0]) * __uint_as_float(wq[ss].x << 16);
      float p1 = exp2f(e0[1]) * __uint_as_float(wq[ss].x & 0xffff0000u);
      float p2 = exp2f(e0[2]) * __uint_as_float(wq[ss].y << 16);
      float p3 = exp2f(e0[3]) * __uint_as_float(wq[ss].y & 0xffff0000u);
      float p4 = exp2f(e1[0]) * __uint_as_float(wq[ss].z << 16);
      float p5 = exp2f(e1[1]) * __uint_as_float(wq[ss].z & 0xffff0000u);
      float p6 = exp2f(e1[2]) * __uint_as_float(wq[ss].w << 16);
      float p7 = exp2f(e1[3]) * __uint_as_float(wq[ss].w & 0xffff0000u);
      unsigned int* pu = (unsigned int*)&pf[ss];
      pu[0] = pkbf(p0, p1); pu[1] = pkbf(p2, p3);
      pu[2] = pkbf(p4, p5); pu[3] = pkbf(p6, p7);
    }
#pragma unroll
    for (int ss = 0; ss < 2; ++ss)
#pragma unroll
      for (int df = 0; df < 4; ++df)
        acc[ss][df] = __builtin_amdgcn_mfma_f32_16x16x32_bf16(pf[ss], vf[df], acc[ss][df], 0, 0, 0);
  }

  // direct output write: O raw [B,H,S,d] contiguous (torch .view is reinterpret)
  float* Og = O + (size_t)(b * NHEAD + h) * S_LEN * HEADD;
#pragma unroll
  for (int ss = 0; ss < 2; ++ss)
#pragma unroll
    for (int df = 0; df < 4; ++df)
#pragma unroll
      for (int r = 0; r < 4; ++r)
        Og[(size_t)(s0 + ss * 16 + quad * 4 + r) * HEADD + df * 16 + l15] = acc[ss][df][r];
}

// ---------------- zero-workspace fallback (round-1 kernel, known correct) ----------------
__global__ __launch_bounds__(512, 2)
void attn_fallback(const float* __restrict__ Qg0, const float* __restrict__ Kg0,
                   const float* __restrict__ Vg0, float* __restrict__ Og0) {
  __shared__ __align__(16) unsigned short Klds[NHEAD][32][72];
  __shared__ __align__(16) unsigned short Vlds[NHEAD][HEADD][40];
  __shared__ __align__(16) unsigned short EA2[NHEAD][64][40];
  const int tid = threadIdx.x, h = tid >> 6, lane = tid & 63, quad = lane >> 4, l15 = lane & 15;
  const int b = blockIdx.x >> 6, s0 = (blockIdx.x & 63) * 64;
  const float* Qg = Qg0 + ((size_t)(b * NHEAD + h)) * S_LEN * HEADD;
  const float* Kg = Kg0 + ((size_t)(b * NHEAD + h)) * HEADD * S_LEN;
  const float* Vg = Vg0 + ((size_t)(b * NHEAD + h)) * S_LEN * HEADD;
  float* Og = Og0 + ((size_t)(b * NHEAD + h)) * S_LEN * HEADD;
  const float SC = 0.04419417382415922f;
  short8 qf[4][2];
#pragma unroll
  for (int ss = 0; ss < 4; ++ss)
#pragma unroll
    for (int kk = 0; kk < 2; ++kk) {
      const float* p = Qg + (size_t)(s0 + ss * 16 + l15) * HEADD + kk * 32 + quad * 8;
      float4v a0 = *(const float4v*)p; float4v a1 = *(const float4v*)(p + 4);
      short8 f;
      f[0] = (short)f2bf(a0[0]); f[1] = (short)f2bf(a0[1]); f[2] = (short)f2bf(a0[2]); f[3] = (short)f2bf(a0[3]);
      f[4] = (short)f2bf(a1[0]); f[5] = (short)f2bf(a1[1]); f[6] = (short)f2bf(a1[2]); f[7] = (short)f2bf(a1[3]);
      qf[ss][kk] = f;
    }
  float4v acc[4][4];
#pragma unroll
  for (int ss = 0; ss < 4; ++ss)
#pragma unroll
    for (int ds = 0; ds < 4; ++ds) acc[ss][ds] = (float4v){0.f, 0.f, 0.f, 0.f};
  const int koct = lane >> 3, kt4 = (lane & 7) * 4, vdq = lane & 15, vtg = lane >> 4;
  const int s_sm = tid >> 3, t4_sm = (tid & 7) * 4;
  for (int it = 0; it < S_LEN / 32; ++it) {
    const int t0 = it * 32;
    {
      float buf[8][4];
#pragma unroll
      for (int j = 0; j < 8; ++j) {
        float4v v = *(const float4v*)(Kg + (size_t)(koct * 8 + j) * S_LEN + t0 + kt4);
        buf[j][0] = v[0]; buf[j][1] = v[1]; buf[j][2] = v[2]; buf[j][3] = v[3];
      }
#pragma unroll
      for (int c = 0; c < 4; ++c) {
        short8 f;
#pragma unroll
        for (int j = 0; j < 8; ++j) f[j] = (short)f2bf(buf[j][c]);
        *(short8*)&Klds[h][kt4 + c][koct * 8] = f;
      }
    }
    {
      float buf[8][4];
#pragma unroll
      for (int j = 0; j < 8; ++j) {
        float4v v = *(const float4v*)(Vg + (size_t)(t0 + vtg * 8 + j) * HEADD + vdq * 4);
        buf[j][0] = v[0]; buf[j][1] = v[1]; buf[j][2] = v[2]; buf[j][3] = v[3];
      }
#pragma unroll
      for (int c = 0; c < 4; ++c) {
        short8 f;
#pragma unroll
        for (int j = 0; j < 8; ++j) f[j] = (short)f2bf(buf[j][c]);
        *(short8*)&Vlds[h][vdq * 4 + c][vtg * 8] = f;
      }
    }
    __syncthreads();
#pragma unroll
    for (int ts = 0; ts < 2; ++ts) {
      short8 kf0 = *(const short8*)&Klds[h][ts * 16 + l15][quad * 8];
      short8 kf1 = *(const short8*)&Klds[h][ts * 16 + l15][32 + quad * 8];
#pragma unroll
      for (int ss = 0; ss < 4; ++ss) {
        float4v e = (float4v){0.f, 0.f, 0.f, 0.f};
        e = __builtin_amdgcn_mfma_f32_16x16x32_bf16(qf[ss][0], kf0, e, 0, 0, 0);
        e = __builtin_amdgcn_mfma_f32_16x16x32_bf16(qf[ss][1], kf1, e, 0, 0, 0);
#pragma unroll
        for (int r = 0; r < 4; ++r)
          EA2[h][ss * 16 + quad * 4 + r][ts * 16 + l15] = __half_as_ushort(__float2half(e[r] * SC));
      }
    }
    __syncthreads();
    {
      float ev[8][4];
#pragma unroll
      for (int hh = 0; hh < 8; ++hh) {
        unsigned long long u = *(const unsigned long long*)&EA2[hh][s_sm][t4_sm];
        ev[hh][0] = __half2float(__ushort_as_half((unsigned short)u));
        ev[hh][1] = __half2float(__ushort_as_half((unsigned short)(u >> 16)));
        ev[hh][2] = __half2float(__ushort_as_half((unsigned short)(u >> 32)));
        ev[hh][3] = __half2float(__ushort_as_half((unsigned short)(u >> 48)));
      }
#pragma unroll
      for (int c = 0; c < 4; ++c) {
        float m = ev[0][c];
#pragma unroll
        for (int hh = 1; hh < 8; ++hh) m = fmaxf(m, ev[hh][c]);
        float sum = 0.f;
#pragma unroll
        for (int hh = 0; hh < 8; ++hh) { float x = __expf(ev[hh][c] - m); ev[hh][c] = x; sum += x; }
        float inv = __builtin_amdgcn_rcpf(sum);
#pragma unroll
        for (int hh = 0; hh < 8; ++hh) ev[hh][c] *= inv;
      }
#pragma unroll
      for (int hh = 0; hh < 8; ++hh) {
        unsigned short u0 = f2bf(ev[hh][0]), u1 = f2bf(ev[hh][1]), u2 = f2bf(ev[hh][2]), u3 = f2bf(ev[hh][3]);
        unsigned long long w = (unsigned long long)u0 | ((unsigned long long)u1 << 16) |
                               ((unsigned long long)u2 << 32) | ((unsigned long long)u3 << 48);
        *(unsigned long long*)&EA2[hh][s_sm][t4_sm] = w;
      }
    }
    __syncthreads();
    {
      short8 af[4], vf[4];
#pragma unroll
      for (int ss = 0; ss < 4; ++ss) af[ss] = *(const short8*)&EA2[h][ss * 16 + l15][quad * 8];
#pragma unroll
      for (int ds = 0; ds < 4; ++ds) vf[ds] = *(const short8*)&Vlds[h][ds * 16 + l15][quad * 8];
#pragma unroll
      for (int ss = 0; ss < 4; ++ss)
#pragma unroll
        for (int ds = 0; ds < 4; ++ds)
          acc[ss][ds] = __builtin_amdgcn_mfma_f32_16x16x32_bf16(af[ss], vf[ds], acc[ss][ds], 0, 0, 0);
    }
    __syncthreads();
  }
#pragma unroll
  for (int ss = 0; ss < 4; ++ss)
#pragma unroll
    for (int ds = 0; ds < 4; ++ds)
#pragma unroll
      for (int r = 0; r < 4; ++r)
        Og[(size_t)(s0 + ss * 16 + quad * 4 + r) * HEADD + ds * 16 + l15] = acc[ss][ds][r];
}

extern "C" void kernel_launch(void* const* d_in, const int* in_sizes, int n_in,
                              void* d_out, int out_size, void* d_ws, size_t ws_size,
                              hipStream_t stream) {
  const float* Q = (const float*)d_in[0];
  const float* K = (const float*)d_in[1];
  const float* V = (const float*)d_in[2];
  float* O = (float*)d_out;

  if (ws_size >= WS_FULL) {
    unsigned short* Kt = (unsigned short*)d_ws;
    unsigned short* Vt = (unsigned short*)((char*)d_ws + VT_OFF);
    unsigned int* Wq   = (unsigned int*)((char*)d_ws + WQ_OFF);
    hipLaunchKernelGGL(prepass_cvt, dim3(1024), dim3(256), 0, stream, K, V, Kt, Vt);
    hipLaunchKernelGGL(z_pass,  dim3(2048), dim3(256), 0, stream, Q, Kt, Wq);
    hipLaunchKernelGGL(pv_pass, dim3(256),  dim3(512), 0, stream, Q, Kt, Vt, Wq, O);
  } else {
    hipLaunchKernelGGL(attn_fallback, dim3(128), dim3(512), 0, stream, Q, K, V, O);
  }
}